// Round 13
// baseline (39.592 us; speedup 1.0000x reference)
//
#include <hip/hip_runtime.h>

// 3-NN IDW upsampling, round 13: r12 math at full occupancy.
//  - THREADS=1024 (16 waves), Q=4, NSPLIT=64 (lane=split -> contiguous
//    conflict-free b128 scan reads), PPB=64, grid 512 = 2 blocks/CU
//    -> 32 waves/CU (8/SIMD, max). __launch_bounds__(1024,8) caps VGPR at 64.
//  - Conflict-free staging: thread t owns points {t, t+1024, ...}: coalesced
//    b32 global reads, lane-contiguous b128 LDS writes.
//  - Scan identical to r12: AoS {x,y,z,|p|^2}, dot-form v2 = (qq+1e-3)
//    - 2q.p + pp (3 FMA + 1 add), truncated packed keys, top-3 med3 insert.
//  - Merge: 64 splits x top-3 -> 16 chunks x top-4-of-12 (retention 4/12 >
//    r12's 5/24, strictly safer) -> 64 -> top-8 -> exact-f64 re-rank + f64
//    IDW epilogue verbatim (passed r1-r12; absmax 0.00390625).

constexpr int S_SPARSE = 4096;
constexpr int NSPLIT   = 64;                 // lane split of S per query
constexpr int Q        = 4;                  // queries per thread
constexpr int THREADS  = 1024;               // 16 waves
constexpr int PPB      = 64;                 // queries per block
constexpr int NITER    = S_SPARSE / NSPLIT;  // 64 scan iters per lane
constexpr int K        = 3;                  // per-split top-K kept
constexpr int KA       = 4;                  // stage-A top-K per 12-key chunk
constexpr int KM       = 8;                  // final candidates for f64 re-rank
constexpr int KROW     = NSPLIT * K + 5;     // 197 dwords (odd: breaks stride)
constexpr int KBUF2_OFF_DW = PPB * KROW;     // 12608 dwords
constexpr int PQ_PAD   = 128;                // prefetch overrun + kbuf2 room

__device__ __forceinline__ unsigned med3u(unsigned a, unsigned b, unsigned c) {
    unsigned d;
    asm("v_med3_u32 %0, %1, %2, %3" : "=v"(d) : "v"(a), "v"(b), "v"(c));
    return d;
}

__global__ __launch_bounds__(THREADS, 8)
void upsample_knn3(const float* __restrict__ xyz,
                   const float* __restrict__ sxyz,
                   const float* __restrict__ sflow,
                   float* __restrict__ out,
                   int N)
{
    // 66 KiB: AoS float4 sparse points during scan; aliased as key-exchange
    // buffers afterwards (epilogue re-reads coords from global/L2).
    // kbuf usage: 12608 (lists) + 4096 (stage A out) = 16704 dw <= 16896 dw.
    __shared__ __align__(16) unsigned char smem_raw[(S_SPARSE + PQ_PAD) * 16];
    float4*   pq   = reinterpret_cast<float4*>(smem_raw);
    unsigned* kbuf = reinterpret_cast<unsigned*>(smem_raw);

    const int t   = threadIdx.x;
    const int s   = t & 63;                  // lane = split
    const int g   = t >> 6;                  // wave = query group 0..15
    const int b   = blockIdx.y;
    const int chk = blockIdx.x;              // 0..255

    // ---- stage sparse points as AoS {x,y,z,|p|^2}; conflict-free writes ----
    const float* sx = sxyz + (size_t)b * 3 * S_SPARSE;
    const float* sy = sx + S_SPARSE;
    const float* sz = sy + S_SPARSE;
    #pragma unroll
    for (int e = 0; e < S_SPARSE / THREADS; ++e) {   // 4 iters
        const int idx = e * THREADS + t;             // coalesced b32 reads
        const float px = sx[idx], py = sy[idx], pz = sz[idx];
        const float pp = fmaf(pz, pz, fmaf(py, py, px * px));
        pq[idx] = make_float4(px, py, pz, pp);       // lane-contiguous b128
    }

    // ---- my 4 query points: precompute -2q and qq + bias ----
    const float* xb = xyz + (size_t)b * 3 * N;
    const int p0 = chk * PPB + g * Q;
    float m2x[Q], m2y[Q], m2z[Q], qqc[Q];
    {
        const float4 x0 = *reinterpret_cast<const float4*>(xb + p0);
        const float4 y0 = *reinterpret_cast<const float4*>(xb + N + p0);
        const float4 z0 = *reinterpret_cast<const float4*>(xb + 2 * N + p0);
        #pragma unroll
        for (int q = 0; q < Q; ++q) {
            const float qx = (&x0.x)[q];
            const float qy = (&y0.x)[q];
            const float qz = (&z0.x)[q];
            m2x[q] = -2.0f * qx;
            m2y[q] = -2.0f * qy;
            m2z[q] = -2.0f * qz;
            qqc[q] = fmaf(qz, qz, fmaf(qy, qy, qx * qx)) + 1e-3f;
        }
    }
    __syncthreads();

    // ---- scan: 1 ds_read_b128/point, 8 ops/pair, top-3 med3 insert ----
    unsigned k0[Q], k1[Q], k2[Q];
    #pragma unroll
    for (int q = 0; q < Q; ++q) { k0[q]=0xFFFFFFFFu; k1[q]=0xFFFFFFFFu; k2[q]=0xFFFFFFFFu; }

    float4 cur = pq[s];
    #pragma unroll 4
    for (int i = 0; i < NITER; ++i) {
        const int j = (i << 6) | s;
        const float4 nxt = pq[j + 64];       // last-iter prefetch lands in pad
        #pragma unroll
        for (int q = 0; q < Q; ++q) {
            const float v  = fmaf(m2x[q], cur.x,
                             fmaf(m2y[q], cur.y,
                             fmaf(m2z[q], cur.z, qqc[q])));
            const float v2 = v + cur.w;      // = d2 + 1e-3 (+-5e-6), > 0
            const unsigned c = (__float_as_uint(v2) & 0xFFFFF000u) | (unsigned)j;
            k2[q] = med3u(k1[q], k2[q], c);
            k1[q] = med3u(k0[q], k1[q], c);
            k0[q] = min(k0[q], c);
        }
        cur = nxt;
    }

    // ---- publish per-split sorted-3 lists (alias over pq) ----
    __syncthreads();
    #pragma unroll
    for (int q = 0; q < Q; ++q) {
        const int base = (g * Q + q) * KROW + s * K;   // lane stride 3: 2-way, free
        kbuf[base + 0] = k0[q];
        kbuf[base + 1] = k1[q];
        kbuf[base + 2] = k2[q];
    }
    __syncthreads();

    // ---- merge stage A: 16 threads/query, each folds 12 keys -> top-4 ----
    {
        const int lp = t >> 4;               // local query 0..63
        const int ch = t & 15;               // chunk 0..15
        unsigned m0=0xFFFFFFFFu, m1=0xFFFFFFFFu, m2=0xFFFFFFFFu, m3=0xFFFFFFFFu;
        const unsigned* rowp = kbuf + lp * KROW + ch * 12;
        #pragma unroll
        for (int c = 0; c < 12; ++c) {
            const unsigned cc = rowp[c];
            m3 = med3u(m2, m3, cc);
            m2 = med3u(m1, m2, cc);
            m1 = med3u(m0, m1, cc);
            m0 = min(m0, cc);
        }
        unsigned* o = kbuf + KBUF2_OFF_DW + (lp * 16 + ch) * KA;
        o[0]=m0; o[1]=m1; o[2]=m2; o[3]=m3;
    }
    __syncthreads();

    // ---- merge stage B + exact-f64 re-rank + f64 IDW (t < 64) ----
    if (t < PPB) {
        unsigned bk[KM];
        #pragma unroll
        for (int k = 0; k < KM; ++k) bk[k] = 0xFFFFFFFFu;
        const unsigned* inp = kbuf + KBUF2_OFF_DW + t * 16 * KA;
        #pragma unroll
        for (int c = 0; c < 16 * KA; ++c) {
            const unsigned cc = inp[c];
            bk[7] = med3u(bk[6], bk[7], cc);
            bk[6] = med3u(bk[5], bk[6], cc);
            bk[5] = med3u(bk[4], bk[5], cc);
            bk[4] = med3u(bk[3], bk[4], cc);
            bk[3] = med3u(bk[2], bk[3], cc);
            bk[2] = med3u(bk[1], bk[2], cc);
            bk[1] = med3u(bk[0], bk[1], cc);
            bk[0] = min(bk[0], cc);
        }

        // exact-f64 re-rank of 8 candidates (identical to rounds 1-12)
        const int pt = chk * PPB + t;
        const double qxd = (double)xb[pt];
        const double qyd = (double)xb[N + pt];
        const double qzd = (double)xb[2 * N + pt];

        double e0 = 1e300, e1 = 1e300, e2 = 1e300;
        int    j0 = 0,     j1 = 0,     j2 = 0;
        #pragma unroll
        for (int c = 0; c < KM; ++c) {
            const int    j  = (int)(bk[c] & 0xFFFu);
            const double dx = qxd - (double)sx[j];
            const double dy = qyd - (double)sy[j];
            const double dz = qzd - (double)sz[j];
            const double d2 = dx * dx + dy * dy + dz * dz;
            if (d2 < e2) {
                if (d2 < e1) {
                    e2 = e1; j2 = j1;
                    if (d2 < e0) { e1 = e0; j1 = j0; e0 = d2; j0 = j; }
                    else         { e1 = d2; j1 = j; }
                } else {
                    e2 = d2; j2 = j;
                }
            }
        }

        double dist0 = sqrt(e0); dist0 = dist0 > 1e-10 ? dist0 : 1e-10;
        double dist1 = sqrt(e1); dist1 = dist1 > 1e-10 ? dist1 : 1e-10;
        double dist2 = sqrt(e2); dist2 = dist2 > 1e-10 ? dist2 : 1e-10;
        const double inv0 = 1.0 / dist0;
        const double inv1 = 1.0 / dist1;
        const double inv2 = 1.0 / dist2;
        const double wsum = inv0 + inv1 + inv2;

        const float* fb = sflow + (size_t)b * 3 * S_SPARSE;
        float*       ob = out   + (size_t)b * 3 * N;
        #pragma unroll
        for (int c = 0; c < 3; ++c) {
            const float* fc = fb + c * S_SPARSE;
            const double o =
                (inv0 * (double)fc[j0] +
                 inv1 * (double)fc[j1] +
                 inv2 * (double)fc[j2]) / wsum;
            ob[c * N + pt] = (float)o;
        }
    }
}

extern "C" void kernel_launch(void* const* d_in, const int* in_sizes, int n_in,
                              void* d_out, int out_size, void* d_ws, size_t ws_size,
                              hipStream_t stream)
{
    const float* xyz  = (const float*)d_in[0];
    const float* sxyz = (const float*)d_in[1];
    const float* sflw = (const float*)d_in[2];
    float*       out  = (float*)d_out;

    const int B = 2;
    const int N = in_sizes[0] / (3 * B);     // 16384

    dim3 grid(N / PPB, B);                   // 256 x 2 = 512 blocks, 2/CU
    upsample_knn3<<<grid, THREADS, 0, stream>>>(xyz, sxyz, sflw, out, N);
}